// Round 1
// baseline (233.951 us; speedup 1.0000x reference)
//
#include <hip/hip_runtime.h>
#include <math.h>

static constexpr int kB = 8, kC = 32, kR = 255, kE = 256;

// Static device scratch (graph-capture-safe, no d_ws dependence).
__device__ float g_qw[4 * 256];      // (q0_h^T W_k,h) * scale, per head  [h][e]
__device__ float g_s0[4];            // score at key position 0, per head (scaled)
__device__ float g_qb[4];            // (q0_h . b_k,h) * scale
__device__ float g_vcls[256];        // v projection of cls token
__device__ float g_wvT[256 * 256];   // [e][f] = w_qkv[512+f][e]
__device__ float g_woutT[256 * 256]; // [e][g] = w_out[g][e]
__device__ float g_w1T[256 * 1024];  // [e][f] = w1[f][e]
__device__ float g_w2T[1024 * 256];  // [f][e] = w2[e][f]

__global__ __launch_bounds__(256) void k_setup(const float* __restrict__ cls,
                                               const float* __restrict__ w_qkv,
                                               const float* __restrict__ b_qkv) {
  __shared__ float clss[256], q0s[256], kcs[256];
  const int t = threadIdx.x;
  clss[t] = cls[t];
  __syncthreads();
  float a0 = b_qkv[t], a1 = b_qkv[256 + t], a2 = b_qkv[512 + t];
  const float* r0 = w_qkv + (size_t)t * 256;
  const float* r1 = w_qkv + (size_t)(256 + t) * 256;
  const float* r2 = w_qkv + (size_t)(512 + t) * 256;
#pragma unroll 4
  for (int e = 0; e < 256; ++e) {
    float ce = clss[e];
    a0 += r0[e] * ce;
    a1 += r1[e] * ce;
    a2 += r2[e] * ce;
  }
  q0s[t] = a0;
  kcs[t] = a1;
  g_vcls[t] = a2;
  __syncthreads();
  const float scale = 0.125f;  // 1/sqrt(64)
#pragma unroll
  for (int h = 0; h < 4; ++h) {
    float acc = 0.f;
    for (int j = 0; j < 64; ++j)
      acc += q0s[h * 64 + j] * w_qkv[(size_t)(256 + h * 64 + j) * 256 + t];
    g_qw[h * 256 + t] = acc * scale;
  }
  if (t < 4) {
    float qb = 0.f, s0 = 0.f;
    for (int j = 0; j < 64; ++j) {
      float q = q0s[t * 64 + j];
      qb += q * b_qkv[256 + t * 64 + j];
      s0 += q * kcs[t * 64 + j];  // kcs already includes b_k
    }
    g_qb[t] = qb * scale;
    g_s0[t] = s0 * scale;
  }
}

__global__ __launch_bounds__(256) void k_transpose(const float* __restrict__ w_qkv,
                                                   const float* __restrict__ w_out,
                                                   const float* __restrict__ w1,
                                                   const float* __restrict__ w2) {
  const int z = blockIdx.z;
  const float* in;
  float* out;
  int Rn, Cn;
  if (z == 0) { in = w_qkv + 512 * 256; out = g_wvT;   Rn = 256;  Cn = 256; }
  else if (z == 1) { in = w_out;        out = g_woutT; Rn = 256;  Cn = 256; }
  else if (z == 2) { in = w1;           out = g_w1T;   Rn = 1024; Cn = 256; }
  else { in = w2;                       out = g_w2T;   Rn = 256;  Cn = 1024; }
  const int c0 = blockIdx.x * 32, r0 = blockIdx.y * 32;
  if (c0 >= Cn || r0 >= Rn) return;
  __shared__ float tile[32][33];
  const int tx = threadIdx.x, ty = threadIdx.y;  // blockDim (32, 8)
#pragma unroll
  for (int i = 0; i < 32; i += 8)
    tile[ty + i][tx] = in[(size_t)(r0 + ty + i) * Cn + c0 + tx];
  __syncthreads();
#pragma unroll
  for (int i = 0; i < 32; i += 8)
    out[(size_t)(c0 + ty + i) * Rn + r0 + tx] = tile[tx][ty + i];
}

__global__ __launch_bounds__(256) void k_main(
    const float* __restrict__ x, const int* __restrict__ real_cols,
    const int* __restrict__ real_rows, const float* __restrict__ b_qkv,
    const float* __restrict__ b_out, const float* __restrict__ ln_g,
    const float* __restrict__ ln_b, const float* __restrict__ b1,
    const float* __restrict__ b2, float* __restrict__ out) {
  const int t = threadIdx.x;
  const int wv = t >> 6, l = t & 63;
  const int bc = blockIdx.x, b = bc >> 5, c = bc & 31;
  float* orow = out + (size_t)bc * kE;
  if (c >= real_cols[b]) {  // invalid column -> zeros (block-uniform branch)
    orow[t] = 0.f;
    return;
  }
  const int rr = real_rows[b];  // valid key positions: 0..rr (x rows 0..rr-1)

  __shared__ float sc[4][256];        // scores -> probabilities
  __shared__ float xpart[4][4][256];  // per-wave partial weighted sums
  __shared__ float xb[4][256];        // xbar per head
  __shared__ float p0s[4];
  __shared__ float ctxs[256];
  __shared__ float lns[256];
  __shared__ float h1s[1024];
  __shared__ float rbuf[2][4];

  float4 qw4[4];
#pragma unroll
  for (int h = 0; h < 4; ++h) qw4[h] = *(const float4*)&g_qw[h * 256 + 4 * l];
  const float qb0 = g_qb[0], qb1 = g_qb[1], qb2 = g_qb[2], qb3 = g_qb[3];
  if (t < 4) sc[t][0] = g_s0[t];

  const float* xbase = x + (size_t)bc * kR * kE;

  // Phase 1: scores for key positions 1..rr (wave wv handles s = wv+1, wv+5, ...)
#pragma unroll 2
  for (int s = 1 + wv; s <= rr; s += 4) {
    float4 xv = *(const float4*)(xbase + (size_t)(s - 1) * kE + 4 * l);
    float p0 = qw4[0].x * xv.x + qw4[0].y * xv.y + qw4[0].z * xv.z + qw4[0].w * xv.w;
    float p1 = qw4[1].x * xv.x + qw4[1].y * xv.y + qw4[1].z * xv.z + qw4[1].w * xv.w;
    float p2 = qw4[2].x * xv.x + qw4[2].y * xv.y + qw4[2].z * xv.z + qw4[2].w * xv.w;
    float p3 = qw4[3].x * xv.x + qw4[3].y * xv.y + qw4[3].z * xv.z + qw4[3].w * xv.w;
#pragma unroll
    for (int m = 1; m < 64; m <<= 1) {
      p0 += __shfl_xor(p0, m);
      p1 += __shfl_xor(p1, m);
      p2 += __shfl_xor(p2, m);
      p3 += __shfl_xor(p3, m);
    }
    if (l == 0) {
      sc[0][s] = p0 + qb0;
      sc[1][s] = p1 + qb1;
      sc[2][s] = p2 + qb2;
      sc[3][s] = p3 + qb3;
    }
  }
  __syncthreads();

  // Softmax: wave wv owns head wv over positions 0..rr
  {
    float mx = -1e30f;
    for (int s = l; s <= rr; s += 64) mx = fmaxf(mx, sc[wv][s]);
#pragma unroll
    for (int m = 1; m < 64; m <<= 1) mx = fmaxf(mx, __shfl_xor(mx, m));
    float sum = 0.f;
    for (int s = l; s <= rr; s += 64) {
      float p = __expf(sc[wv][s] - mx);
      sc[wv][s] = p;
      sum += p;
    }
#pragma unroll
    for (int m = 1; m < 64; m <<= 1) sum += __shfl_xor(sum, m);
    const float inv = 1.f / sum;
    for (int s = l; s <= rr; s += 64) sc[wv][s] *= inv;
    if (l == 0) p0s[wv] = sc[wv][0];
  }
  __syncthreads();

  // Phase 2: xbar_h = sum_{s=1..rr} p[h][s] * x_row(s-1)
  float4 a0 = {0, 0, 0, 0}, a1 = {0, 0, 0, 0}, a2 = {0, 0, 0, 0}, a3 = {0, 0, 0, 0};
#pragma unroll 2
  for (int s = 1 + wv; s <= rr; s += 4) {
    float4 xv = *(const float4*)(xbase + (size_t)(s - 1) * kE + 4 * l);
    float w0 = sc[0][s], w1w = sc[1][s], w2w = sc[2][s], w3w = sc[3][s];
    a0.x += w0 * xv.x;  a0.y += w0 * xv.y;  a0.z += w0 * xv.z;  a0.w += w0 * xv.w;
    a1.x += w1w * xv.x; a1.y += w1w * xv.y; a1.z += w1w * xv.z; a1.w += w1w * xv.w;
    a2.x += w2w * xv.x; a2.y += w2w * xv.y; a2.z += w2w * xv.z; a2.w += w2w * xv.w;
    a3.x += w3w * xv.x; a3.y += w3w * xv.y; a3.z += w3w * xv.z; a3.w += w3w * xv.w;
  }
  *(float4*)&xpart[wv][0][4 * l] = a0;
  *(float4*)&xpart[wv][1][4 * l] = a1;
  *(float4*)&xpart[wv][2][4 * l] = a2;
  *(float4*)&xpart[wv][3][4 * l] = a3;
  __syncthreads();
#pragma unroll
  for (int h = 0; h < 4; ++h)
    xb[h][t] = xpart[0][h][t] + xpart[1][h][t] + xpart[2][h][t] + xpart[3][h][t];
  __syncthreads();

  // ctx[f] = p0*v_cls[f] + (1-p0)*b_v[f] + W_v,h(f) . xbar_h(f)
  {
    const float p0h = p0s[wv];
    float acc = p0h * g_vcls[t] + (1.f - p0h) * b_qkv[512 + t];
#pragma unroll 8
    for (int e = 0; e < 256; ++e) acc += g_wvT[e * 256 + t] * xb[wv][e];
    ctxs[t] = acc;
  }
  __syncthreads();

  // mha[g] = b_out[g] + W_out[g,:] . ctx
  float mh = b_out[t];
#pragma unroll 8
  for (int e = 0; e < 256; ++e) mh += g_woutT[e * 256 + t] * ctxs[e];

  // LayerNorm over the 256 features
  float s1v = mh, s2v = mh * mh;
#pragma unroll
  for (int m = 1; m < 64; m <<= 1) {
    s1v += __shfl_xor(s1v, m);
    s2v += __shfl_xor(s2v, m);
  }
  if (l == 0) {
    rbuf[0][wv] = s1v;
    rbuf[1][wv] = s2v;
  }
  __syncthreads();
  const float mu = (rbuf[0][0] + rbuf[0][1] + rbuf[0][2] + rbuf[0][3]) * (1.f / 256.f);
  const float msq = (rbuf[1][0] + rbuf[1][1] + rbuf[1][2] + rbuf[1][3]) * (1.f / 256.f);
  const float var = msq - mu * mu;
  const float lnv = (mh - mu) * rsqrtf(var + 1e-5f) * ln_g[t] + ln_b[t];
  lns[t] = lnv;
  __syncthreads();

  // FFN1: h = relu(W1 . ln + b1), 1024 outputs, 4 per thread
  float h0 = b1[t], h1v = b1[t + 256], h2v = b1[t + 512], h3v = b1[t + 768];
#pragma unroll 4
  for (int e = 0; e < 256; ++e) {
    const float le = lns[e];
    const float* wp = &g_w1T[(size_t)e * 1024 + t];
    h0 += wp[0] * le;
    h1v += wp[256] * le;
    h2v += wp[512] * le;
    h3v += wp[768] * le;
  }
  h1s[t] = fmaxf(h0, 0.f);
  h1s[t + 256] = fmaxf(h1v, 0.f);
  h1s[t + 512] = fmaxf(h2v, 0.f);
  h1s[t + 768] = fmaxf(h3v, 0.f);
  __syncthreads();

  // FFN2 + residual
  float f2 = b2[t];
#pragma unroll 8
  for (int f = 0; f < 1024; ++f) f2 += g_w2T[(size_t)f * 256 + t] * h1s[f];
  orow[t] = lnv + f2;
}

extern "C" void kernel_launch(void* const* d_in, const int* in_sizes, int n_in,
                              void* d_out, int out_size, void* d_ws, size_t ws_size,
                              hipStream_t stream) {
  const float* x = (const float*)d_in[0];
  const int* real_cols = (const int*)d_in[1];
  const int* real_rows = (const int*)d_in[2];
  const float* cls = (const float*)d_in[3];
  const float* w_qkv = (const float*)d_in[4];
  const float* b_qkv = (const float*)d_in[5];
  const float* w_out = (const float*)d_in[6];
  const float* b_out = (const float*)d_in[7];
  const float* ln_g = (const float*)d_in[8];
  const float* ln_b = (const float*)d_in[9];
  const float* w1 = (const float*)d_in[10];
  const float* b1 = (const float*)d_in[11];
  const float* w2 = (const float*)d_in[12];
  const float* b2 = (const float*)d_in[13];
  float* out = (float*)d_out;
  (void)in_sizes; (void)n_in; (void)out_size; (void)d_ws; (void)ws_size;
  (void)ln_g; (void)ln_b;

  k_setup<<<1, 256, 0, stream>>>(cls, w_qkv, b_qkv);
  k_transpose<<<dim3(32, 32, 4), dim3(32, 8), 0, stream>>>(w_qkv, w_out, w1, w2);
  k_main<<<kB * kC, 256, 0, stream>>>(x, real_cols, real_rows, b_qkv, b_out,
                                      ln_g, ln_b, b1, b2, out);
}

// Round 2
// 190.545 us; speedup vs baseline: 1.2278x; 1.2278x over previous
//
#include <hip/hip_runtime.h>
#include <math.h>

static constexpr int kC = 32, kR = 255, kE = 256;

// Static device scratch (graph-capture-safe; avoids d_ws whose size is unknown).
__device__ float g_q0kv[768];            // [q0 | kc | vc] = W_{q,k,v}·cls + b
__device__ float g_qw[4 * 256];          // (q0_h^T W_k,h)*scale  [h][e]
__device__ float g_s0[4];                // score of key position 0 per head
__device__ float g_qb[4];                // (q0_h · b_k,h)*scale
__device__ float g_m[256 * 4 * 4];       // chunk max   [bc][chunk][h]
__device__ float g_l[256 * 4 * 4];       // chunk sum   [bc][chunk][h]
__device__ float g_part[256 * 4 * 4 * 256]; // partial xbar [bc][chunk][h][e]
__device__ float g_ln[256 * 256];        // LN output per token
__device__ float g_hact[256 * 1024];     // FFN hidden activations

// ---- Setup 1: rows of W_qkv · cls + b_qkv (768 dots), wave-per-row ----
__global__ __launch_bounds__(256) void k_setup1(const float* __restrict__ cls,
                                                const float* __restrict__ w_qkv,
                                                const float* __restrict__ b_qkv) {
  const int t = threadIdx.x, wv = t >> 6, l = t & 63;
  const int row = blockIdx.x * 4 + wv;  // 0..767
  float4 wv4 = *(const float4*)(w_qkv + (size_t)row * 256 + 4 * l);
  float4 cv4 = *(const float4*)(cls + 4 * l);
  float acc = wv4.x * cv4.x + wv4.y * cv4.y + wv4.z * cv4.z + wv4.w * cv4.w;
#pragma unroll
  for (int m = 1; m < 64; m <<= 1) acc += __shfl_xor(acc, m);
  if (l == 0) g_q0kv[row] = acc + b_qkv[row];
}

// ---- Setup 2: per-head qw row, s0, qb. One block per head. ----
__global__ __launch_bounds__(256) void k_setup2(const float* __restrict__ w_qkv,
                                                const float* __restrict__ b_qkv) {
  const int h = blockIdx.x, t = threadIdx.x;
  __shared__ float q0s[64];
  if (t < 64) q0s[t] = g_q0kv[h * 64 + t];
  __syncthreads();
  float acc = 0.f;
#pragma unroll 8
  for (int j = 0; j < 64; ++j)
    acc += q0s[j] * w_qkv[(size_t)(256 + h * 64 + j) * 256 + t];
  g_qw[h * 256 + t] = acc * 0.125f;
  if (t < 64) {
    float q = q0s[t];
    float pk = q * g_q0kv[256 + h * 64 + t];  // kc already includes b_k
    float pb = q * b_qkv[256 + h * 64 + t];
#pragma unroll
    for (int m = 1; m < 64; m <<= 1) {
      pk += __shfl_xor(pk, m);
      pb += __shfl_xor(pb, m);
    }
    if (t == 0) {
      g_s0[h] = pk * 0.125f;
      g_qb[h] = pb * 0.125f;
    }
  }
}

// ---- Attention chunks: scores + chunk softmax + partial weighted sums ----
__global__ __launch_bounds__(256) void k_attn(const float* __restrict__ x,
                                              const int* __restrict__ real_cols,
                                              const int* __restrict__ real_rows) {
  const int bc = blockIdx.x, chunk = blockIdx.y;
  const int b = bc >> 5, c = bc & 31;
  if (c >= real_cols[b]) return;
  const int rr = real_rows[b];
  const int r0 = chunk * 64;
  const int nr = min(64, rr - r0);
  if (nr <= 0) return;

  __shared__ float xsT[256][65];  // [e][row], stride 65 -> conflict-free both ways
  __shared__ float qws[4 * 256];
  __shared__ float ps[4][64];
  const int t = threadIdx.x, wv = t >> 6, l = t & 63;

#pragma unroll
  for (int i = 0; i < 4; ++i) qws[i * 256 + t] = g_qw[i * 256 + t];

  const float* xb = x + ((size_t)bc * kR + r0) * kE;
  for (int r = wv; r < nr; r += 4) {
    float4 v = *(const float4*)(xb + (size_t)r * kE + 4 * l);
    xsT[4 * l + 0][r] = v.x;
    xsT[4 * l + 1][r] = v.y;
    xsT[4 * l + 2][r] = v.z;
    xsT[4 * l + 3][r] = v.w;
  }
  __syncthreads();

  // scores: thread = (row=l, head=wv)
  const int h = wv, row = l;
  float acc = 0.f;
#pragma unroll 8
  for (int e = 0; e < 256; ++e) acc += qws[h * 256 + e] * xsT[e][row];
  float s = (row < nr) ? acc + g_qb[h] : -1e30f;
  float mx = s;
#pragma unroll
  for (int m = 1; m < 64; m <<= 1) mx = fmaxf(mx, __shfl_xor(mx, m));
  float p = (row < nr) ? __expf(s - mx) : 0.f;
  float lsum = p;
#pragma unroll
  for (int m = 1; m < 64; m <<= 1) lsum += __shfl_xor(lsum, m);
  ps[h][row] = p;
  if (l == 0) {
    g_m[(bc * 4 + chunk) * 4 + h] = mx;
    g_l[(bc * 4 + chunk) * 4 + h] = lsum;
  }
  __syncthreads();

  // partial weighted sums: thread t owns element e=t
  float a0 = 0.f, a1 = 0.f, a2 = 0.f, a3 = 0.f;
  for (int r2 = 0; r2 < nr; ++r2) {
    float xv = xsT[t][r2];
    a0 += ps[0][r2] * xv;
    a1 += ps[1][r2] * xv;
    a2 += ps[2][r2] * xv;
    a3 += ps[3][r2] * xv;
  }
  float* pp = g_part + (size_t)(bc * 4 + chunk) * 4 * 256;
  pp[0 * 256 + t] = a0;
  pp[1 * 256 + t] = a1;
  pp[2 * 256 + t] = a2;
  pp[3 * 256 + t] = a3;
}

// ---- Tail 1: merge chunks -> xbar -> ctx -> mha -> LN. 4 tokens/block ----
__global__ __launch_bounds__(256) void k_tail1(const int* __restrict__ real_cols,
                                               const int* __restrict__ real_rows,
                                               const float* __restrict__ w_qkv,
                                               const float* __restrict__ w_out,
                                               const float* __restrict__ b_qkv,
                                               const float* __restrict__ b_out,
                                               const float* __restrict__ ln_g,
                                               const float* __restrict__ ln_b) {
  const int t = threadIdx.x;
  const int tok0 = blockIdx.x * 4;
  __shared__ float xb4[4][4][256];
  __shared__ float ctx4[4][256];
  __shared__ float mh4[4][256];
  __shared__ float al[4][4][4];
  __shared__ float p04[4][4];
  __shared__ float stats[4][2];
  __shared__ int valids[4];

  if (t < 16) {  // i = t>>2 token, h = t&3 head
    const int i = t >> 2, h = t & 3, bc = tok0 + i, b = bc >> 5, c = bc & 31;
    const int valid = (c < real_cols[b]);
    if (h == 0) valids[i] = valid;
    float a0 = 0.f, a1 = 0.f, a2 = 0.f, a3 = 0.f, p0 = 0.f;
    if (valid) {
      const int rr = real_rows[b];
      const int nch = (rr + 63) >> 6;
      const float s0 = g_s0[h];
      float M = s0;
      for (int ch = 0; ch < nch; ++ch) M = fmaxf(M, g_m[(bc * 4 + ch) * 4 + h]);
      float av[4] = {0.f, 0.f, 0.f, 0.f};
      float lt = __expf(s0 - M);
      const float w0 = lt;
      for (int ch = 0; ch < nch; ++ch) {
        float e = __expf(g_m[(bc * 4 + ch) * 4 + h] - M);
        av[ch] = e;
        lt += g_l[(bc * 4 + ch) * 4 + h] * e;
      }
      const float inv = 1.f / lt;
      a0 = av[0] * inv; a1 = av[1] * inv; a2 = av[2] * inv; a3 = av[3] * inv;
      p0 = w0 * inv;
    }
    al[i][h][0] = a0; al[i][h][1] = a1; al[i][h][2] = a2; al[i][h][3] = a3;
    p04[i][h] = p0;
  }
  __syncthreads();

  // xbar for 4 tokens (al==0 chunks multiply stale-but-finite data by zero)
#pragma unroll
  for (int i = 0; i < 4; ++i) {
    const int bc = tok0 + i;
#pragma unroll
    for (int h = 0; h < 4; ++h) {
      const float* pp = g_part + (size_t)bc * 4 * 4 * 256 + h * 256 + t;
      float a = al[i][h][0] * pp[0] + al[i][h][1] * pp[4 * 256] +
                al[i][h][2] * pp[8 * 256] + al[i][h][3] * pp[12 * 256];
      xb4[i][h][t] = a;
    }
  }
  __syncthreads();

  // ctx[f=t]: weight row read once, reused for 4 tokens
  {
    const int h = t >> 6;
    const float* wrow = w_qkv + (size_t)(512 + t) * 256;
    const float vc = g_q0kv[512 + t];  // includes b_v
    const float bv = b_qkv[512 + t];
    float acc[4];
#pragma unroll
    for (int i = 0; i < 4; ++i) acc[i] = p04[i][h] * vc + (1.f - p04[i][h]) * bv;
    for (int e = 0; e < 256; e += 4) {
      float4 w4 = *(const float4*)(wrow + e);
#pragma unroll
      for (int i = 0; i < 4; ++i)
        acc[i] += w4.x * xb4[i][h][e] + w4.y * xb4[i][h][e + 1] +
                  w4.z * xb4[i][h][e + 2] + w4.w * xb4[i][h][e + 3];
    }
#pragma unroll
    for (int i = 0; i < 4; ++i) ctx4[i][t] = acc[i];
  }
  __syncthreads();

  // mha[g=t]
  {
    const float* wrow = w_out + (size_t)t * 256;
    const float bo = b_out[t];
    float acc[4];
#pragma unroll
    for (int i = 0; i < 4; ++i) acc[i] = bo;
    for (int e = 0; e < 256; e += 4) {
      float4 w4 = *(const float4*)(wrow + e);
#pragma unroll
      for (int i = 0; i < 4; ++i)
        acc[i] += w4.x * ctx4[i][e] + w4.y * ctx4[i][e + 1] +
                  w4.z * ctx4[i][e + 2] + w4.w * ctx4[i][e + 3];
    }
#pragma unroll
    for (int i = 0; i < 4; ++i) mh4[i][t] = acc[i];
  }
  __syncthreads();

  // LN stats: wave wv handles token wv
  {
    const int i = t >> 6, l = t & 63;
    float s1 = 0.f, s2 = 0.f;
#pragma unroll
    for (int k = 0; k < 4; ++k) {
      float v = mh4[i][l + 64 * k];
      s1 += v;
      s2 += v * v;
    }
#pragma unroll
    for (int m = 1; m < 64; m <<= 1) {
      s1 += __shfl_xor(s1, m);
      s2 += __shfl_xor(s2, m);
    }
    if (l == 0) {
      float mu = s1 * (1.f / 256.f);
      float var = s2 * (1.f / 256.f) - mu * mu;
      stats[i][0] = mu;
      stats[i][1] = rsqrtf(var + 1e-5f);
    }
  }
  __syncthreads();
  const float lg = ln_g[t], lb = ln_b[t];
#pragma unroll
  for (int i = 0; i < 4; ++i)
    g_ln[(size_t)(tok0 + i) * 256 + t] =
        (mh4[i][t] - stats[i][0]) * stats[i][1] * lg + lb;
}

// ---- FFN1: h = relu(W1·ln + b1). Tile: 8 tokens x 128 features ----
__global__ __launch_bounds__(256) void k_ffn1(const float* __restrict__ w1,
                                              const float* __restrict__ b1) {
  __shared__ float lns[8][256];
  const int t = threadIdx.x;
  const int tok0 = blockIdx.x * 8, f0 = blockIdx.y * 128;
#pragma unroll
  for (int i = 0; i < 8; ++i) lns[i][t] = g_ln[(size_t)(tok0 + i) * 256 + t];
  __syncthreads();
  const int f = f0 + (t & 127), half = t >> 7;  // half 0 -> tokens 0..3, half 1 -> 4..7
  const float* wrow = w1 + (size_t)f * 256;
  const float bb = b1[f];
  float acc[4] = {bb, bb, bb, bb};
  for (int e = 0; e < 256; e += 4) {
    float4 w4 = *(const float4*)(wrow + e);
#pragma unroll
    for (int k = 0; k < 4; ++k) {
      const int i = half * 4 + k;
      acc[k] += w4.x * lns[i][e] + w4.y * lns[i][e + 1] +
                w4.z * lns[i][e + 2] + w4.w * lns[i][e + 3];
    }
  }
#pragma unroll
  for (int k = 0; k < 4; ++k)
    g_hact[(size_t)(tok0 + half * 4 + k) * 1024 + f] = fmaxf(acc[k], 0.f);
}

// ---- FFN2 + residual + column mask. Tile: 8 tokens x 32 outputs ----
__global__ __launch_bounds__(256) void k_ffn2(const float* __restrict__ w2,
                                              const float* __restrict__ b2,
                                              const int* __restrict__ real_cols,
                                              float* __restrict__ out) {
  __shared__ float hs[8][1024];  // 32 KB
  const int t = threadIdx.x;
  const int tok0 = blockIdx.x * 8, e0 = blockIdx.y * 32;
#pragma unroll
  for (int i = 0; i < 8; ++i) {
#pragma unroll
    for (int j = 0; j < 4; ++j)
      hs[i][j * 256 + t] = g_hact[(size_t)(tok0 + i) * 1024 + j * 256 + t];
  }
  __syncthreads();
  const int e = e0 + (t & 31), i = t >> 5;  // one token per 32-thread group
  const int tok = tok0 + i, b = tok >> 5, c = tok & 31;
  const float* wrow = w2 + (size_t)e * 1024;
  float acc = b2[e];
  for (int f = 0; f < 1024; f += 4) {
    float4 w4 = *(const float4*)(wrow + f);
    acc += w4.x * hs[i][f] + w4.y * hs[i][f + 1] + w4.z * hs[i][f + 2] +
           w4.w * hs[i][f + 3];
  }
  const float lnv = g_ln[(size_t)tok * 256 + e];
  out[(size_t)tok * 256 + e] = (c < real_cols[b]) ? (lnv + acc) : 0.f;
}

extern "C" void kernel_launch(void* const* d_in, const int* in_sizes, int n_in,
                              void* d_out, int out_size, void* d_ws, size_t ws_size,
                              hipStream_t stream) {
  const float* x = (const float*)d_in[0];
  const int* real_cols = (const int*)d_in[1];
  const int* real_rows = (const int*)d_in[2];
  const float* cls = (const float*)d_in[3];
  const float* w_qkv = (const float*)d_in[4];
  const float* b_qkv = (const float*)d_in[5];
  const float* w_out = (const float*)d_in[6];
  const float* b_out = (const float*)d_in[7];
  const float* ln_g = (const float*)d_in[8];
  const float* ln_b = (const float*)d_in[9];
  const float* w1 = (const float*)d_in[10];
  const float* b1 = (const float*)d_in[11];
  const float* w2 = (const float*)d_in[12];
  const float* b2 = (const float*)d_in[13];
  float* out = (float*)d_out;
  (void)in_sizes; (void)n_in; (void)out_size; (void)d_ws; (void)ws_size;

  k_setup1<<<192, 256, 0, stream>>>(cls, w_qkv, b_qkv);
  k_setup2<<<4, 256, 0, stream>>>(w_qkv, b_qkv);
  k_attn<<<dim3(256, 4), 256, 0, stream>>>(x, real_cols, real_rows);
  k_tail1<<<64, 256, 0, stream>>>(real_cols, real_rows, w_qkv, w_out, b_qkv,
                                  b_out, ln_g, ln_b);
  k_ffn1<<<dim3(32, 8), 256, 0, stream>>>(w1, b1);
  k_ffn2<<<dim3(32, 8), 256, 0, stream>>>(w2, b2, real_cols, out);
}